// Round 2
// baseline (1340.185 us; speedup 1.0000x reference)
//
#include <hip/hip_runtime.h>
#include <hip/hip_bf16.h>

// ---------------- problem constants ----------------
constexpr int U_  = 51200;
constexpr int I_  = 25600;
constexpr int D_  = 64;
constexpr int E_  = 1000000;
constexpr int EP_ = 100000;
constexpr int CB_ = 256;                 // contrastive chunk size
constexpr int NCHUNK_ = U_ / CB_;        // 200
constexpr size_t UD_ = (size_t)U_ * D_;  // 3276800
constexpr size_t ID_ = (size_t)I_ * D_;  // 1638400

// ---------------- workspace layout (float offsets) ----------------
constexpr size_t OFF_U1   = 0;
constexpr size_t OFF_U2   = OFF_U1 + UD_;
constexpr size_t OFF_I1   = OFF_U2 + UD_;
constexpr size_t OFF_I2   = OFF_I1 + ID_;
constexpr size_t OFF_DEGU = OFF_I2 + ID_;
constexpr size_t OFF_DEGI = OFF_DEGU + U_;
constexpr size_t OFF_LOSS = OFF_DEGI + I_;
constexpr size_t MEMSET_BYTES = (OFF_LOSS + 1) * sizeof(float); // zero accumulators
constexpr size_t OFF_HU   = OFF_LOSS + 64;   // padded to keep 256B alignment
constexpr size_t OFF_HI   = OFF_HU + UD_;
constexpr size_t OFF_ANC  = OFF_HI + ID_;
constexpr size_t OFF_WA   = OFF_ANC + UD_;
constexpr size_t OFF_FLAG = OFF_WA + 64;
// total ≈ 72.4 MB

#define DEVI static __device__ __forceinline__

typedef _Float16 h2v __attribute__((ext_vector_type(2)));

DEVI float b2f(__hip_bfloat16 x) { return __bfloat162float(x); }

// dtype-agnostic load: isf32 ? float buffer : bf16 buffer
DEVI float ldf(const void* p, size_t i, int isf32) {
  if (isf32) return ((const float*)p)[i];
  return b2f(((const __hip_bfloat16*)p)[i]);
}

DEVI float fdot2f(h2v a, h2v b, float c) {
#if __has_builtin(__builtin_amdgcn_fdot2)
  return __builtin_amdgcn_fdot2(a, b, c, false);
#else
  return (float)a[0] * (float)b[0] + (float)a[1] * (float)b[1] + c;
#endif
}
DEVI unsigned h2u(h2v h) { unsigned u; __builtin_memcpy(&u, &h, 4); return u; }
DEVI h2v u2h(unsigned u) { h2v h; __builtin_memcpy(&h, &u, 4); return h; }
DEVI float frcp(float x) { return __builtin_amdgcn_rcpf(x); }

// ---------------- 0. dtype detection ----------------
// bf16 data ~N(0,0.01): no 16-bit word decodes (as bf16) to |x|>=8.
// f32 data read as 16-bit words: low halves have uniform-random exponent
// fields -> ~25% of all words decode to |x|>=8 or inf/nan.
__global__ void detect_kernel(const unsigned short* __restrict__ p,
                              float* __restrict__ flag) {
  int cnt = 0;
  for (int i = 0; i < 256; i++) {
    int e = (p[i] >> 7) & 0xFF;
    if (e >= 130) cnt++;
  }
  *flag = (cnt >= 8) ? 1.0f : 0.0f;
}

// ---------------- 1. propagation (scatter-mean via atomics) ----------------
__global__ __launch_bounds__(256) void prop1_kernel(
    const void* __restrict__ ue, const void* __restrict__ ie,
    const int* __restrict__ rs, const int* __restrict__ rd,
    float* __restrict__ i1, float* __restrict__ u1,
    float* __restrict__ degu, float* __restrict__ degi,
    const float* __restrict__ flag) {
  int isf32 = *flag > 0.5f;
  int tid = blockIdx.x * 256 + threadIdx.x;    // E*64 threads
  int e = tid >> 6, d = tid & 63;
  int src = rs[e], dst = rd[e];
  atomicAdd(&i1[(size_t)dst * 64 + d], ldf(ue, (size_t)src * 64 + d, isf32));
  atomicAdd(&u1[(size_t)src * 64 + d], ldf(ie, (size_t)dst * 64 + d, isf32));
  if (d == 0) {
    atomicAdd(&degi[dst], 1.0f);
    atomicAdd(&degu[src], 1.0f);
  }
}

__global__ __launch_bounds__(256) void prop2_kernel(
    const float* __restrict__ u1, const float* __restrict__ i1,
    const int* __restrict__ rs, const int* __restrict__ rd,
    float* __restrict__ i2, float* __restrict__ u2) {
  int tid = blockIdx.x * 256 + threadIdx.x;
  int e = tid >> 6, d = tid & 63;
  int src = rs[e], dst = rd[e];
  atomicAdd(&i2[(size_t)dst * 64 + d], u1[(size_t)src * 64 + d]);
  atomicAdd(&u2[(size_t)src * 64 + d], i1[(size_t)dst * 64 + d]);
}

__global__ __launch_bounds__(256) void norm_kernel(
    float* __restrict__ ub, float* __restrict__ ib,
    const float* __restrict__ degu, const float* __restrict__ degi) {
  size_t t = (size_t)blockIdx.x * 256 + threadIdx.x;  // UD_+ID_ threads
  if (t < UD_) {
    ub[t] /= fmaxf(degu[t >> 6], 1.0f);
  } else {
    size_t s = t - UD_;
    ib[s] /= fmaxf(degi[s >> 6], 1.0f);
  }
}

// ---------------- 2. layer attention ----------------
__global__ void wa_kernel(const void* __restrict__ W, const void* __restrict__ a,
                          float* __restrict__ Wa, const float* __restrict__ flag) {
  int isf32 = *flag > 0.5f;
  int d = threadIdx.x;  // 64 threads
  float s = 0.f;
  for (int e = 0; e < 64; e++) s += ldf(W, d * 64 + e, isf32) * ldf(a, e, isf32);
  Wa[d] = s;
}

__global__ __launch_bounds__(256) void attn_kernel(
    const void* __restrict__ l0, const float* __restrict__ l1,
    const float* __restrict__ l2, const float* __restrict__ Wa,
    float* __restrict__ out, const float* __restrict__ flag) {
  int isf32 = *flag > 0.5f;
  int node = blockIdx.x * 4 + (threadIdx.x >> 6);
  int lane = threadIdx.x & 63;
  size_t idx = (size_t)node * 64 + lane;
  float t0 = ldf(l0, idx, isf32);
  float t1 = l1[idx];
  float t2 = l2[idx];
  float w = Wa[lane];
  float p0 = t0 * w, p1 = t1 * w, p2 = t2 * w;
  #pragma unroll
  for (int off = 32; off; off >>= 1) {
    p0 += __shfl_xor(p0, off, 64);
    p1 += __shfl_xor(p1, off, 64);
    p2 += __shfl_xor(p2, off, 64);
  }
  float m = fmaxf(p0, fmaxf(p1, p2));
  float e0 = __expf(p0 - m), e1 = __expf(p1 - m), e2 = __expf(p2 - m);
  float inv = 1.0f / (e0 + e1 + e2);
  out[idx] = (t0 * e0 + t1 * e1 + t2 * e2) * inv;
}

// ---------------- 3. anchor user embed (FFT filter + attention) ----------------
__global__ __launch_bounds__(256) void anchor_kernel(
    const void* __restrict__ ue, const void* __restrict__ WU,
    const void* __restrict__ aU, const void* __restrict__ cw,
    const int* __restrict__ nbr, float* __restrict__ out,
    const float* __restrict__ flag) {
  int isf32 = *flag > 0.5f;
  __shared__ __align__(16) float sf[4][8][64];   // filtered simu per wave
  __shared__ __align__(16) float urow[4][64];    // user row per wave
  int wv = threadIdx.x >> 6, lane = threadIdx.x & 63;
  int u = blockIdx.x * 4 + wv;

  float x[8];
  #pragma unroll
  for (int k = 0; k < 8; k++) {
    int nb = nbr[u * 8 + k];
    x[k] = ldf(ue, (size_t)nb * 64 + lane, isf32);
  }
  // 8-point rfft (unscaled); 'ortho' fwd+inv scaling folded into final 1/8
  const float c1 = 0.70710678118654752440f;
  float sA = x[1] - x[3] - x[5] + x[7];
  float sB = x[1] + x[3] - x[5] - x[7];
  float ev = (x[0] + x[4]) + (x[2] + x[6]);
  float od = (x[1] + x[5]) + (x[3] + x[7]);
  float d04 = x[0] - x[4], d26 = x[2] - x[6];
  float X0r = ev + od;
  float X1r = d04 + c1 * sA;
  float X1i = -d26 - c1 * sB;
  float X2r = (x[0] + x[4]) - (x[2] + x[6]);
  float X2i = -(x[1] - x[3] + x[5] - x[7]);
  float X3r = d04 - c1 * sA;
  float X3i = d26 - c1 * sB;
  float X4r = ev - od;
  // complex weight: cw layout [NF][D][2]
  float Zr0 = X0r * ldf(cw, (0 * 64 + lane) * 2, isf32);
  float w1r = ldf(cw, (1 * 64 + lane) * 2, isf32), w1i = ldf(cw, (1 * 64 + lane) * 2 + 1, isf32);
  float Zr1 = X1r * w1r - X1i * w1i, Zi1 = X1r * w1i + X1i * w1r;
  float w2r = ldf(cw, (2 * 64 + lane) * 2, isf32), w2i = ldf(cw, (2 * 64 + lane) * 2 + 1, isf32);
  float Zr2 = X2r * w2r - X2i * w2i, Zi2 = X2r * w2i + X2i * w2r;
  float w3r = ldf(cw, (3 * 64 + lane) * 2, isf32), w3i = ldf(cw, (3 * 64 + lane) * 2 + 1, isf32);
  float Zr3 = X3r * w3r - X3i * w3i, Zi3 = X3r * w3i + X3i * w3r;
  float Zr4 = X4r * ldf(cw, (4 * 64 + lane) * 2, isf32);
  // irfft (C2R drops Im of bins 0 and 4)
  float eP = Zr0 + Zr4, eM = Zr0 - Zr4;
  float t1 = c1 * (Zr1 - Zr3), t2 = c1 * (Zi1 + Zi3);
  float y[8];
  y[0] = eP + 2.f * (Zr1 + Zr2 + Zr3);
  y[1] = eM + 2.f * (t1 - t2 - Zi2);
  y[2] = eP + 2.f * (-Zi1 - Zr2 + Zi3);
  y[3] = eM + 2.f * (-t1 - t2 + Zi2);
  y[4] = eP + 2.f * (-Zr1 + Zr2 - Zr3);
  y[5] = eM + 2.f * (-t1 + t2 - Zi2);
  y[6] = eP + 2.f * (Zi1 - Zr2 - Zi3);
  y[7] = eM + 2.f * (t1 + t2 + Zi2);
  #pragma unroll
  for (int k = 0; k < 8; k++) sf[wv][k][lane] = y[k] * 0.125f;
  urow[wv][lane] = ldf(ue, (size_t)u * 64 + lane, isf32);
  __syncthreads();

  // Wsimu[k][lane] = sum_d sf[k][d]*WU[d][lane];  Wu[lane] = sum_d urow[d]*WU[d][lane]
  float acc[8] = {0, 0, 0, 0, 0, 0, 0, 0};
  float wu = 0.f;
  for (int eg = 0; eg < 16; eg++) {
    float4 uq4 = ((const float4*)urow[wv])[eg];
    float uq[4] = {uq4.x, uq4.y, uq4.z, uq4.w};
    float sq[8][4];
    #pragma unroll
    for (int k = 0; k < 8; k++) {
      float4 q = ((const float4*)sf[wv][k])[eg];
      sq[k][0] = q.x; sq[k][1] = q.y; sq[k][2] = q.z; sq[k][3] = q.w;
    }
    #pragma unroll
    for (int j = 0; j < 4; j++) {
      float wval = ldf(WU, (eg * 4 + j) * 64 + lane, isf32);
      wu += uq[j] * wval;
      #pragma unroll
      for (int k = 0; k < 8; k++) acc[k] += sq[k][j] * wval;
    }
  }
  float aU1 = ldf(aU, lane, isf32), aU2 = ldf(aU, 64 + lane, isf32);
  float ek[8];
  #pragma unroll
  for (int k = 0; k < 8; k++) ek[k] = acc[k] * aU1;
  float q = wu * aU2;
  #pragma unroll
  for (int off = 32; off; off >>= 1) {
    #pragma unroll
    for (int k = 0; k < 8; k++) ek[k] += __shfl_xor(ek[k], off, 64);
    q += __shfl_xor(q, off, 64);
  }
  float m = -1e30f;
  #pragma unroll
  for (int k = 0; k < 8; k++) {
    float v = ek[k] + q;
    v = v > 0.f ? v : 0.1f * v;  // LeakyReLU(0.1)
    ek[k] = v;
    m = fmaxf(m, v);
  }
  float se = 0.f, wexp[8];
  #pragma unroll
  for (int k = 0; k < 8; k++) { wexp[k] = __expf(ek[k] - m); se += wexp[k]; }
  float o = 0.f;
  #pragma unroll
  for (int k = 0; k < 8; k++) o += wexp[k] * acc[k];
  out[(size_t)u * 64 + lane] = o / se;
}

// ---------------- 4. contrastive loss (per 256-row chunk) ----------------
__global__ __launch_bounds__(256) void contrast_kernel(
    const float* __restrict__ hu, const float* __restrict__ an,
    float* __restrict__ loss_acc) {
  __shared__ uint4 L1[CB_ * 8];  // 32KB: normalized hu rows as f16
  __shared__ uint4 L2[CB_ * 8];  // 32KB: normalized anchor rows as f16
  __shared__ float N1[CB_], N2[CB_];
  int tid = threadIdx.x, c = blockIdx.x;
  const float* r1 = hu + ((size_t)c * CB_ + tid) * 64;
  const float* r2 = an + ((size_t)c * CB_ + tid) * 64;
  float s1 = 0.f, s2 = 0.f;
  #pragma unroll
  for (int t = 0; t < 16; t++) {
    float4 a = ((const float4*)r1)[t];
    s1 += a.x * a.x + a.y * a.y + a.z * a.z + a.w * a.w;
    float4 b = ((const float4*)r2)[t];
    s2 += b.x * b.x + b.y * b.y + b.z * b.z + b.w * b.w;
  }
  float n1 = sqrtf(s1), n2 = sqrtf(s2);
  float inv1 = frcp(n1), inv2 = frcp(n2);
  N1[tid] = n1; N2[tid] = n2;
  h2v h1[32], g2[32];
  #pragma unroll
  for (int t = 0; t < 16; t++) {
    float4 a = ((const float4*)r1)[t];
    h2v p; p[0] = (_Float16)(a.x * inv1); p[1] = (_Float16)(a.y * inv1); h1[2 * t] = p;
    h2v q; q[0] = (_Float16)(a.z * inv1); q[1] = (_Float16)(a.w * inv1); h1[2 * t + 1] = q;
    float4 b = ((const float4*)r2)[t];
    h2v r; r[0] = (_Float16)(b.x * inv2); r[1] = (_Float16)(b.y * inv2); g2[2 * t] = r;
    h2v s; s[0] = (_Float16)(b.z * inv2); s[1] = (_Float16)(b.w * inv2); g2[2 * t + 1] = s;
  }
  #pragma unroll
  for (int t = 0; t < 8; t++) {
    uint4 p = {h2u(h1[4 * t]), h2u(h1[4 * t + 1]), h2u(h1[4 * t + 2]), h2u(h1[4 * t + 3])};
    L1[tid * 8 + t] = p;
    uint4 q = {h2u(g2[4 * t]), h2u(g2[4 * t + 1]), h2u(g2[4 * t + 2]), h2u(g2[4 * t + 3])};
    L2[tid * 8 + t] = q;
  }
  __syncthreads();

  float sum_t = 0.f, sum_b = 0.f, labT = 0.f, labB = 0.f;
  for (int j = 0; j < CB_; j++) {
    float d11 = 0.f, d12 = 0.f, d21 = 0.f, d22 = 0.f;
    #pragma unroll
    for (int t = 0; t < 8; t++) {
      uint4 a1 = L1[j * 8 + t];
      uint4 a2 = L2[j * 8 + t];
      h2v b;
      b = u2h(a1.x); d11 = fdot2f(h1[4 * t + 0], b, d11); d21 = fdot2f(g2[4 * t + 0], b, d21);
      b = u2h(a1.y); d11 = fdot2f(h1[4 * t + 1], b, d11); d21 = fdot2f(g2[4 * t + 1], b, d21);
      b = u2h(a1.z); d11 = fdot2f(h1[4 * t + 2], b, d11); d21 = fdot2f(g2[4 * t + 2], b, d21);
      b = u2h(a1.w); d11 = fdot2f(h1[4 * t + 3], b, d11); d21 = fdot2f(g2[4 * t + 3], b, d21);
      b = u2h(a2.x); d12 = fdot2f(h1[4 * t + 0], b, d12); d22 = fdot2f(g2[4 * t + 0], b, d22);
      b = u2h(a2.y); d12 = fdot2f(h1[4 * t + 1], b, d12); d22 = fdot2f(g2[4 * t + 1], b, d22);
      b = u2h(a2.z); d12 = fdot2f(h1[4 * t + 2], b, d12); d22 = fdot2f(g2[4 * t + 2], b, d22);
      b = u2h(a2.w); d12 = fdot2f(h1[4 * t + 3], b, d12); d22 = fdot2f(g2[4 * t + 3], b, d22);
    }
    // exact reference semantics: s = dot/(n_i*n_j + 1e-6)/TEMP, dot = cos*n_i*n_j
    float m1 = N1[j], m2 = N2[j];
    float p11 = n1 * m1, p12 = n1 * m2, p21 = n2 * m1, p22 = n2 * m2;
    d11 *= 5.0f * p11 * frcp(p11 + 1e-6f);
    d12 *= 5.0f * p12 * frcp(p12 + 1e-6f);
    d21 *= 5.0f * p21 * frcp(p21 + 1e-6f);
    d22 *= 5.0f * p22 * frcp(p22 + 1e-6f);
    float e12 = __expf(d12), e21 = __expf(d21);
    if (j == tid) {  // diag of s-terms masked; labels = c12/c21 diag
      labT = d12; labB = d21;
      sum_t += e12; sum_b += e21;
    } else {
      sum_t += __expf(d11) + e12;
      sum_b += __expf(d22) + e21;
    }
  }
  float loss = (__logf(sum_t) - labT) + (__logf(sum_b) - labB);
  #pragma unroll
  for (int off = 32; off; off >>= 1) loss += __shfl_xor(loss, off, 64);
  if ((tid & 63) == 0) atomicAdd(loss_acc, loss);
}

// ---------------- 5. scores ----------------
__global__ __launch_bounds__(256) void score_kernel(
    const float* __restrict__ hu, const float* __restrict__ hi,
    const int* __restrict__ pu, const int* __restrict__ pi,
    const int* __restrict__ nu, const int* __restrict__ ni,
    void* __restrict__ out, const float* __restrict__ flag) {
  int isf32 = *flag > 0.5f;
  int w = (blockIdx.x * 256 + threadIdx.x) >> 6;  // 2*EP waves
  int lane = threadIdx.x & 63;
  int uu, ii;
  if (w < EP_) { uu = pu[w]; ii = pi[w]; }
  else         { uu = nu[w - EP_]; ii = ni[w - EP_]; }
  float p = hu[(size_t)uu * 64 + lane] * hi[(size_t)ii * 64 + lane];
  #pragma unroll
  for (int off = 32; off; off >>= 1) p += __shfl_xor(p, off, 64);
  if (lane == 0) {
    if (isf32) ((float*)out)[w] = p;
    else       ((__hip_bfloat16*)out)[w] = __float2bfloat16(p);
  }
}

__global__ void finalize_kernel(const float* __restrict__ loss_acc,
                                void* __restrict__ out,
                                const float* __restrict__ flag) {
  float v = loss_acc[0] * (1.0f / (float)(2 * CB_ * NCHUNK_));
  if (*flag > 0.5f) ((float*)out)[2 * EP_] = v;
  else              ((__hip_bfloat16*)out)[2 * EP_] = __float2bfloat16(v);
}

// ---------------- launch ----------------
extern "C" void kernel_launch(void* const* d_in, const int* in_sizes, int n_in,
                              void* d_out, int out_size, void* d_ws, size_t ws_size,
                              hipStream_t stream) {
  const void* ue  = d_in[0];
  const void* ie  = d_in[1];
  const void* W   = d_in[2];
  const void* a   = d_in[3];
  const void* WU  = d_in[4];
  const void* aU  = d_in[5];
  const void* cw  = d_in[6];
  const int* rs  = (const int*)d_in[7];
  const int* rd  = (const int*)d_in[8];
  const int* pu  = (const int*)d_in[9];
  const int* pi  = (const int*)d_in[10];
  const int* nu  = (const int*)d_in[11];
  const int* ni  = (const int*)d_in[12];
  const int* nbr = (const int*)d_in[13];

  float* wsf   = (float*)d_ws;
  float* u1    = wsf + OFF_U1;
  float* u2    = wsf + OFF_U2;
  float* i1    = wsf + OFF_I1;
  float* i2    = wsf + OFF_I2;
  float* degu  = wsf + OFF_DEGU;
  float* degi  = wsf + OFF_DEGI;
  float* loss  = wsf + OFF_LOSS;
  float* hu    = wsf + OFF_HU;
  float* hi    = wsf + OFF_HI;
  float* anc   = wsf + OFF_ANC;
  float* Wa    = wsf + OFF_WA;
  float* flag  = wsf + OFF_FLAG;

  hipMemsetAsync(d_ws, 0, MEMSET_BYTES, stream);
  detect_kernel<<<1, 1, 0, stream>>>((const unsigned short*)ue, flag);

  // propagation layer 1 + degrees
  prop1_kernel<<<(E_ * 64) / 256, 256, 0, stream>>>(ue, ie, rs, rd, i1, u1, degu, degi, flag);
  norm_kernel<<<(int)((UD_ + ID_) / 256), 256, 0, stream>>>(u1, i1, degu, degi);
  // propagation layer 2
  prop2_kernel<<<(E_ * 64) / 256, 256, 0, stream>>>(u1, i1, rs, rd, i2, u2);
  norm_kernel<<<(int)((UD_ + ID_) / 256), 256, 0, stream>>>(u2, i2, degu, degi);

  // layer attention
  wa_kernel<<<1, 64, 0, stream>>>(W, a, Wa, flag);
  attn_kernel<<<U_ / 4, 256, 0, stream>>>(ue, u1, u2, Wa, hu, flag);
  attn_kernel<<<I_ / 4, 256, 0, stream>>>(ie, i1, i2, Wa, hi, flag);

  // anchor path
  anchor_kernel<<<U_ / 4, 256, 0, stream>>>(ue, WU, aU, cw, nbr, anc, flag);

  // contrastive loss
  contrast_kernel<<<NCHUNK_, 256, 0, stream>>>(hu, anc, loss);

  // scores
  score_kernel<<<(2 * EP_ * 64) / 256, 256, 0, stream>>>(hu, hi, pu, pi, nu, ni, d_out, flag);
  finalize_kernel<<<1, 1, 0, stream>>>(loss, d_out, flag);
}

// Round 3
// 796.280 us; speedup vs baseline: 1.6831x; 1.6831x over previous
//
#include <hip/hip_runtime.h>
#include <hip/hip_bf16.h>

// ---------------- problem constants ----------------
constexpr int U_  = 51200;
constexpr int I_  = 25600;
constexpr int N_  = U_ + I_;             // 76800 combined rows
constexpr int E_  = 1000000;
constexpr int EP_ = 100000;
constexpr int CB_ = 256;                 // contrastive chunk size
constexpr int NCHUNK_ = U_ / CB_;        // 200
constexpr size_t UD_ = (size_t)U_ * 64;
constexpr size_t ID_ = (size_t)I_ * 64;
constexpr int NB_ = N_ / 1024;           // 75 scan blocks

// ---------------- workspace layout (4-byte element offsets) ----------------
constexpr size_t OFF_LOSS  = 0;
constexpr size_t OFF_FLAG  = 1;
constexpr size_t OFF_WA    = 64;
constexpr size_t OFF_CUR   = 128;                    // N_ ints (histogram, then cursor)
constexpr size_t MEMSET_BYTES = (OFF_CUR + N_) * 4;  // zero loss/flag/Wa/cur
constexpr size_t OFF_RTMP  = OFF_CUR + N_;           // N_ ints
constexpr size_t OFF_BSUM  = OFF_RTMP + N_;          // NB_ ints
constexpr size_t OFF_BOFF  = OFF_BSUM + 128;         // NB_ ints
constexpr size_t OFF_ROWU  = OFF_BOFF + 128;         // U_+1 ints
constexpr size_t OFF_ROWI  = OFF_ROWU + U_ + 1;      // I_+1 ints
constexpr size_t OFF_CSRU  = ((OFF_ROWI + I_ + 1 + 63) / 64) * 64;  // E_ ints
constexpr size_t OFF_CSRI  = OFF_CSRU + E_;          // E_ ints
constexpr size_t OFF_U1    = ((OFF_CSRI + E_ + 63) / 64) * 64;
constexpr size_t OFF_I1    = OFF_U1 + UD_;
constexpr size_t OFF_HU    = OFF_I1 + ID_;
constexpr size_t OFF_HI    = OFF_HU + UD_;
constexpr size_t OFF_ANC   = OFF_HI + ID_;
// total ≈ 61.4 MB

#define DEVI static __device__ __forceinline__

typedef _Float16 h2v __attribute__((ext_vector_type(2)));

DEVI float b2f(__hip_bfloat16 x) { return __bfloat162float(x); }

// dtype-agnostic load: isf32 ? float buffer : bf16 buffer
DEVI float ldf(const void* p, size_t i, int isf32) {
  if (isf32) return ((const float*)p)[i];
  return b2f(((const __hip_bfloat16*)p)[i]);
}

DEVI float fdot2f(h2v a, h2v b, float c) {
#if __has_builtin(__builtin_amdgcn_fdot2)
  return __builtin_amdgcn_fdot2(a, b, c, false);
#else
  return (float)a[0] * (float)b[0] + (float)a[1] * (float)b[1] + c;
#endif
}
DEVI unsigned h2u(h2v h) { unsigned u; __builtin_memcpy(&u, &h, 4); return u; }
DEVI h2v u2h(unsigned u) { h2v h; __builtin_memcpy(&h, &u, 4); return h; }
DEVI float frcp(float x) { return __builtin_amdgcn_rcpf(x); }

DEVI int waveInclScan(int v, int lane) {
  #pragma unroll
  for (int off = 1; off < 64; off <<= 1) {
    int t = __shfl_up(v, off, 64);
    if (lane >= off) v += t;
  }
  return v;
}

// ---------------- 0. dtype detection ----------------
__global__ void detect_kernel(const unsigned short* __restrict__ p,
                              float* __restrict__ flag) {
  int cnt = 0;
  for (int i = 0; i < 256; i++) {
    int e = (p[i] >> 7) & 0xFF;
    if (e >= 130) cnt++;
  }
  *flag = (cnt >= 8) ? 1.0f : 0.0f;
}

// ---------------- 1. CSR build ----------------
__global__ __launch_bounds__(256) void hist_kernel(
    const int* __restrict__ rs, const int* __restrict__ rd, int* __restrict__ cur) {
  int e = blockIdx.x * 256 + threadIdx.x;
  if (e >= E_) return;
  atomicAdd(&cur[rs[e]], 1);
  atomicAdd(&cur[U_ + rd[e]], 1);
}

__global__ __launch_bounds__(256) void scanA_kernel(
    const int* __restrict__ cnt, int* __restrict__ rtmp, int* __restrict__ bsum) {
  __shared__ int wsum[4];
  int tid = threadIdx.x, lane = tid & 63, wv = tid >> 6;
  int gid = blockIdx.x * 256 + tid;
  int4 v = ((const int4*)cnt)[gid];
  int s = v.x + v.y + v.z + v.w;
  int inc = waveInclScan(s, lane);
  if (lane == 63) wsum[wv] = inc;
  __syncthreads();
  int wvoff = 0;
  for (int w = 0; w < wv; w++) wvoff += wsum[w];
  int excl = wvoff + inc - s;
  int base = gid * 4;
  rtmp[base]     = excl;
  rtmp[base + 1] = excl + v.x;
  rtmp[base + 2] = excl + v.x + v.y;
  rtmp[base + 3] = excl + v.x + v.y + v.z;
  if (tid == 255) bsum[blockIdx.x] = wvoff + wsum[3];
}

__global__ void scanB_kernel(const int* __restrict__ bsum, int* __restrict__ boff) {
  if (threadIdx.x == 0) {
    int run = 0;
    for (int i = 0; i < NB_; i++) { boff[i] = run; run += bsum[i]; }
  }
}

__global__ __launch_bounds__(256) void scanC_kernel(
    const int* __restrict__ rtmp, const int* __restrict__ boff,
    int* __restrict__ rowU, int* __restrict__ rowI, int* __restrict__ cur) {
  int gid = blockIdx.x * 256 + threadIdx.x;
  int off = boff[blockIdx.x];
  int4 v = ((const int4*)rtmp)[gid];
  int vals[4] = {v.x, v.y, v.z, v.w};
  int base = gid * 4;
  #pragma unroll
  for (int k = 0; k < 4; k++) {
    int i = base + k;
    int val = vals[k] + off;
    if (i < U_) { rowU[i] = val; cur[i] = val; }
    else        { rowI[i - U_] = val - E_; cur[i] = val - E_; }
  }
  if (gid == 0) { rowU[U_] = E_; rowI[I_] = E_; }
}

__global__ __launch_bounds__(256) void fill_kernel(
    const int* __restrict__ rs, const int* __restrict__ rd, int* __restrict__ cur,
    int* __restrict__ csrU, int* __restrict__ csrI) {
  int e = blockIdx.x * 256 + threadIdx.x;
  if (e >= E_) return;
  int s = rs[e], d = rd[e];
  int pU = atomicAdd(&cur[s], 1);
  csrU[pU] = d;
  int pI = atomicAdd(&cur[U_ + d], 1);
  csrI[pI] = s;
}

// ---------------- 2. layer-1 aggregation (gather, normalized) ----------------
__global__ __launch_bounds__(256) void agg1_kernel(
    const void* __restrict__ src, const int* __restrict__ row,
    const int* __restrict__ csr, float* __restrict__ out,
    const float* __restrict__ flag) {
  int isf32 = *flag > 0.5f;
  int wv = threadIdx.x >> 6, lane = threadIdx.x & 63;
  int r = blockIdx.x * 4 + wv;
  int s0 = row[r], s1 = row[r + 1];
  float acc = 0.f;
  int j = s0;
  for (; j + 4 <= s1; j += 4) {
    int a = csr[j], b = csr[j + 1], c = csr[j + 2], d = csr[j + 3];
    float va = ldf(src, (size_t)a * 64 + lane, isf32);
    float vb = ldf(src, (size_t)b * 64 + lane, isf32);
    float vc = ldf(src, (size_t)c * 64 + lane, isf32);
    float vd = ldf(src, (size_t)d * 64 + lane, isf32);
    acc += (va + vb) + (vc + vd);
  }
  for (; j < s1; j++) acc += ldf(src, (size_t)csr[j] * 64 + lane, isf32);
  out[(size_t)r * 64 + lane] = acc / fmaxf((float)(s1 - s0), 1.0f);
}

// ---------------- 3. layer-2 aggregation + fused layer attention ----------------
__global__ __launch_bounds__(256) void agg2attn_kernel(
    const float* __restrict__ opp1,   // layer-1 of other side (gather source)
    const void* __restrict__ base,    // original embeddings (t0)
    const float* __restrict__ own1,   // layer-1 of this side (t1)
    const int* __restrict__ row, const int* __restrict__ csr,
    const float* __restrict__ Wa, float* __restrict__ h,
    const float* __restrict__ flag) {
  int isf32 = *flag > 0.5f;
  int wv = threadIdx.x >> 6, lane = threadIdx.x & 63;
  int r = blockIdx.x * 4 + wv;
  int s0 = row[r], s1 = row[r + 1];
  float acc = 0.f;
  int j = s0;
  for (; j + 4 <= s1; j += 4) {
    int a = csr[j], b = csr[j + 1], c = csr[j + 2], d = csr[j + 3];
    float va = opp1[(size_t)a * 64 + lane];
    float vb = opp1[(size_t)b * 64 + lane];
    float vc = opp1[(size_t)c * 64 + lane];
    float vd = opp1[(size_t)d * 64 + lane];
    acc += (va + vb) + (vc + vd);
  }
  for (; j < s1; j++) acc += opp1[(size_t)csr[j] * 64 + lane];
  size_t idx = (size_t)r * 64 + lane;
  float t2 = acc / fmaxf((float)(s1 - s0), 1.0f);
  float t0 = ldf(base, idx, isf32);
  float t1 = own1[idx];
  float w = Wa[lane];
  float p0 = t0 * w, p1 = t1 * w, p2 = t2 * w;
  #pragma unroll
  for (int off = 32; off; off >>= 1) {
    p0 += __shfl_xor(p0, off, 64);
    p1 += __shfl_xor(p1, off, 64);
    p2 += __shfl_xor(p2, off, 64);
  }
  float m = fmaxf(p0, fmaxf(p1, p2));
  float e0 = __expf(p0 - m), e1 = __expf(p1 - m), e2 = __expf(p2 - m);
  float inv = 1.0f / (e0 + e1 + e2);
  h[idx] = (t0 * e0 + t1 * e1 + t2 * e2) * inv;
}

// ---------------- Wa = W @ a ----------------
__global__ void wa_kernel(const void* __restrict__ W, const void* __restrict__ a,
                          float* __restrict__ Wa, const float* __restrict__ flag) {
  int isf32 = *flag > 0.5f;
  int d = threadIdx.x;  // 64 threads
  float s = 0.f;
  for (int e = 0; e < 64; e++) s += ldf(W, d * 64 + e, isf32) * ldf(a, e, isf32);
  Wa[d] = s;
}

// ---------------- 4. anchor user embed (FFT filter + attention) ----------------
__global__ __launch_bounds__(256) void anchor_kernel(
    const void* __restrict__ ue, const void* __restrict__ WU,
    const void* __restrict__ aU, const void* __restrict__ cw,
    const int* __restrict__ nbr, float* __restrict__ out,
    const float* __restrict__ flag) {
  int isf32 = *flag > 0.5f;
  __shared__ __align__(16) float sf[4][8][64];
  __shared__ __align__(16) float urow[4][64];
  int wv = threadIdx.x >> 6, lane = threadIdx.x & 63;
  int u = blockIdx.x * 4 + wv;

  float x[8];
  #pragma unroll
  for (int k = 0; k < 8; k++) {
    int nb = nbr[u * 8 + k];
    x[k] = ldf(ue, (size_t)nb * 64 + lane, isf32);
  }
  // 8-point rfft (unscaled); 'ortho' fwd+inv scaling folded into final 1/8
  const float c1 = 0.70710678118654752440f;
  float sA = x[1] - x[3] - x[5] + x[7];
  float sB = x[1] + x[3] - x[5] - x[7];
  float ev = (x[0] + x[4]) + (x[2] + x[6]);
  float od = (x[1] + x[5]) + (x[3] + x[7]);
  float d04 = x[0] - x[4], d26 = x[2] - x[6];
  float X0r = ev + od;
  float X1r = d04 + c1 * sA;
  float X1i = -d26 - c1 * sB;
  float X2r = (x[0] + x[4]) - (x[2] + x[6]);
  float X2i = -(x[1] - x[3] + x[5] - x[7]);
  float X3r = d04 - c1 * sA;
  float X3i = d26 - c1 * sB;
  float X4r = ev - od;
  float Zr0 = X0r * ldf(cw, (0 * 64 + lane) * 2, isf32);
  float w1r = ldf(cw, (1 * 64 + lane) * 2, isf32), w1i = ldf(cw, (1 * 64 + lane) * 2 + 1, isf32);
  float Zr1 = X1r * w1r - X1i * w1i, Zi1 = X1r * w1i + X1i * w1r;
  float w2r = ldf(cw, (2 * 64 + lane) * 2, isf32), w2i = ldf(cw, (2 * 64 + lane) * 2 + 1, isf32);
  float Zr2 = X2r * w2r - X2i * w2i, Zi2 = X2r * w2i + X2i * w2r;
  float w3r = ldf(cw, (3 * 64 + lane) * 2, isf32), w3i = ldf(cw, (3 * 64 + lane) * 2 + 1, isf32);
  float Zr3 = X3r * w3r - X3i * w3i, Zi3 = X3r * w3i + X3i * w3r;
  float Zr4 = X4r * ldf(cw, (4 * 64 + lane) * 2, isf32);
  float eP = Zr0 + Zr4, eM = Zr0 - Zr4;
  float t1 = c1 * (Zr1 - Zr3), t2 = c1 * (Zi1 + Zi3);
  float y[8];
  y[0] = eP + 2.f * (Zr1 + Zr2 + Zr3);
  y[1] = eM + 2.f * (t1 - t2 - Zi2);
  y[2] = eP + 2.f * (-Zi1 - Zr2 + Zi3);
  y[3] = eM + 2.f * (-t1 - t2 + Zi2);
  y[4] = eP + 2.f * (-Zr1 + Zr2 - Zr3);
  y[5] = eM + 2.f * (-t1 + t2 - Zi2);
  y[6] = eP + 2.f * (Zi1 - Zr2 - Zi3);
  y[7] = eM + 2.f * (t1 + t2 + Zi2);
  #pragma unroll
  for (int k = 0; k < 8; k++) sf[wv][k][lane] = y[k] * 0.125f;
  urow[wv][lane] = ldf(ue, (size_t)u * 64 + lane, isf32);
  __syncthreads();

  float acc[8] = {0, 0, 0, 0, 0, 0, 0, 0};
  float wu = 0.f;
  for (int eg = 0; eg < 16; eg++) {
    float4 uq4 = ((const float4*)urow[wv])[eg];
    float uq[4] = {uq4.x, uq4.y, uq4.z, uq4.w};
    float sq[8][4];
    #pragma unroll
    for (int k = 0; k < 8; k++) {
      float4 q = ((const float4*)sf[wv][k])[eg];
      sq[k][0] = q.x; sq[k][1] = q.y; sq[k][2] = q.z; sq[k][3] = q.w;
    }
    #pragma unroll
    for (int j = 0; j < 4; j++) {
      float wval = ldf(WU, (eg * 4 + j) * 64 + lane, isf32);
      wu += uq[j] * wval;
      #pragma unroll
      for (int k = 0; k < 8; k++) acc[k] += sq[k][j] * wval;
    }
  }
  float aU1 = ldf(aU, lane, isf32), aU2 = ldf(aU, 64 + lane, isf32);
  float ek[8];
  #pragma unroll
  for (int k = 0; k < 8; k++) ek[k] = acc[k] * aU1;
  float q = wu * aU2;
  #pragma unroll
  for (int off = 32; off; off >>= 1) {
    #pragma unroll
    for (int k = 0; k < 8; k++) ek[k] += __shfl_xor(ek[k], off, 64);
    q += __shfl_xor(q, off, 64);
  }
  float m = -1e30f;
  #pragma unroll
  for (int k = 0; k < 8; k++) {
    float v = ek[k] + q;
    v = v > 0.f ? v : 0.1f * v;  // LeakyReLU(0.1)
    ek[k] = v;
    m = fmaxf(m, v);
  }
  float se = 0.f, wexp[8];
  #pragma unroll
  for (int k = 0; k < 8; k++) { wexp[k] = __expf(ek[k] - m); se += wexp[k]; }
  float o = 0.f;
  #pragma unroll
  for (int k = 0; k < 8; k++) o += wexp[k] * acc[k];
  out[(size_t)u * 64 + lane] = o / se;
}

// ---------------- 5. contrastive loss (per 256-row chunk) ----------------
__global__ __launch_bounds__(256) void contrast_kernel(
    const float* __restrict__ hu, const float* __restrict__ an,
    float* __restrict__ loss_acc) {
  __shared__ uint4 L1[CB_ * 8];
  __shared__ uint4 L2[CB_ * 8];
  __shared__ float N1[CB_], N2[CB_];
  int tid = threadIdx.x, c = blockIdx.x;
  const float* r1 = hu + ((size_t)c * CB_ + tid) * 64;
  const float* r2 = an + ((size_t)c * CB_ + tid) * 64;
  float s1 = 0.f, s2 = 0.f;
  #pragma unroll
  for (int t = 0; t < 16; t++) {
    float4 a = ((const float4*)r1)[t];
    s1 += a.x * a.x + a.y * a.y + a.z * a.z + a.w * a.w;
    float4 b = ((const float4*)r2)[t];
    s2 += b.x * b.x + b.y * b.y + b.z * b.z + b.w * b.w;
  }
  float n1 = sqrtf(s1), n2 = sqrtf(s2);
  float inv1 = frcp(n1), inv2 = frcp(n2);
  N1[tid] = n1; N2[tid] = n2;
  h2v h1[32], g2[32];
  #pragma unroll
  for (int t = 0; t < 16; t++) {
    float4 a = ((const float4*)r1)[t];
    h2v p; p[0] = (_Float16)(a.x * inv1); p[1] = (_Float16)(a.y * inv1); h1[2 * t] = p;
    h2v q; q[0] = (_Float16)(a.z * inv1); q[1] = (_Float16)(a.w * inv1); h1[2 * t + 1] = q;
    float4 b = ((const float4*)r2)[t];
    h2v r; r[0] = (_Float16)(b.x * inv2); r[1] = (_Float16)(b.y * inv2); g2[2 * t] = r;
    h2v s; s[0] = (_Float16)(b.z * inv2); s[1] = (_Float16)(b.w * inv2); g2[2 * t + 1] = s;
  }
  #pragma unroll
  for (int t = 0; t < 8; t++) {
    uint4 p = {h2u(h1[4 * t]), h2u(h1[4 * t + 1]), h2u(h1[4 * t + 2]), h2u(h1[4 * t + 3])};
    L1[tid * 8 + t] = p;
    uint4 q = {h2u(g2[4 * t]), h2u(g2[4 * t + 1]), h2u(g2[4 * t + 2]), h2u(g2[4 * t + 3])};
    L2[tid * 8 + t] = q;
  }
  __syncthreads();

  float sum_t = 0.f, sum_b = 0.f, labT = 0.f, labB = 0.f;
  for (int j = 0; j < CB_; j++) {
    float d11 = 0.f, d12 = 0.f, d21 = 0.f, d22 = 0.f;
    #pragma unroll
    for (int t = 0; t < 8; t++) {
      uint4 a1 = L1[j * 8 + t];
      uint4 a2 = L2[j * 8 + t];
      h2v b;
      b = u2h(a1.x); d11 = fdot2f(h1[4 * t + 0], b, d11); d21 = fdot2f(g2[4 * t + 0], b, d21);
      b = u2h(a1.y); d11 = fdot2f(h1[4 * t + 1], b, d11); d21 = fdot2f(g2[4 * t + 1], b, d21);
      b = u2h(a1.z); d11 = fdot2f(h1[4 * t + 2], b, d11); d21 = fdot2f(g2[4 * t + 2], b, d21);
      b = u2h(a1.w); d11 = fdot2f(h1[4 * t + 3], b, d11); d21 = fdot2f(g2[4 * t + 3], b, d21);
      b = u2h(a2.x); d12 = fdot2f(h1[4 * t + 0], b, d12); d22 = fdot2f(g2[4 * t + 0], b, d22);
      b = u2h(a2.y); d12 = fdot2f(h1[4 * t + 1], b, d12); d22 = fdot2f(g2[4 * t + 1], b, d22);
      b = u2h(a2.z); d12 = fdot2f(h1[4 * t + 2], b, d12); d22 = fdot2f(g2[4 * t + 2], b, d22);
      b = u2h(a2.w); d12 = fdot2f(h1[4 * t + 3], b, d12); d22 = fdot2f(g2[4 * t + 3], b, d22);
    }
    float m1 = N1[j], m2 = N2[j];
    float p11 = n1 * m1, p12 = n1 * m2, p21 = n2 * m1, p22 = n2 * m2;
    d11 *= 5.0f * p11 * frcp(p11 + 1e-6f);
    d12 *= 5.0f * p12 * frcp(p12 + 1e-6f);
    d21 *= 5.0f * p21 * frcp(p21 + 1e-6f);
    d22 *= 5.0f * p22 * frcp(p22 + 1e-6f);
    float e12 = __expf(d12), e21 = __expf(d21);
    if (j == tid) {
      labT = d12; labB = d21;
      sum_t += e12; sum_b += e21;
    } else {
      sum_t += __expf(d11) + e12;
      sum_b += __expf(d22) + e21;
    }
  }
  float loss = (__logf(sum_t) - labT) + (__logf(sum_b) - labB);
  #pragma unroll
  for (int off = 32; off; off >>= 1) loss += __shfl_xor(loss, off, 64);
  if ((tid & 63) == 0) atomicAdd(loss_acc, loss);
}

// ---------------- 6. scores ----------------
__global__ __launch_bounds__(256) void score_kernel(
    const float* __restrict__ hu, const float* __restrict__ hi,
    const int* __restrict__ pu, const int* __restrict__ pi,
    const int* __restrict__ nu, const int* __restrict__ ni,
    void* __restrict__ out, const float* __restrict__ flag) {
  int isf32 = *flag > 0.5f;
  int w = (blockIdx.x * 256 + threadIdx.x) >> 6;
  int lane = threadIdx.x & 63;
  int uu, ii;
  if (w < EP_) { uu = pu[w]; ii = pi[w]; }
  else         { uu = nu[w - EP_]; ii = ni[w - EP_]; }
  float p = hu[(size_t)uu * 64 + lane] * hi[(size_t)ii * 64 + lane];
  #pragma unroll
  for (int off = 32; off; off >>= 1) p += __shfl_xor(p, off, 64);
  if (lane == 0) {
    if (isf32) ((float*)out)[w] = p;
    else       ((__hip_bfloat16*)out)[w] = __float2bfloat16(p);
  }
}

__global__ void finalize_kernel(const float* __restrict__ loss_acc,
                                void* __restrict__ out,
                                const float* __restrict__ flag) {
  float v = loss_acc[0] * (1.0f / (float)(2 * CB_ * NCHUNK_));
  if (*flag > 0.5f) ((float*)out)[2 * EP_] = v;
  else              ((__hip_bfloat16*)out)[2 * EP_] = __float2bfloat16(v);
}

// ---------------- launch ----------------
extern "C" void kernel_launch(void* const* d_in, const int* in_sizes, int n_in,
                              void* d_out, int out_size, void* d_ws, size_t ws_size,
                              hipStream_t stream) {
  const void* ue  = d_in[0];
  const void* ie  = d_in[1];
  const void* W   = d_in[2];
  const void* a   = d_in[3];
  const void* WU  = d_in[4];
  const void* aU  = d_in[5];
  const void* cw  = d_in[6];
  const int* rs  = (const int*)d_in[7];
  const int* rd  = (const int*)d_in[8];
  const int* pu  = (const int*)d_in[9];
  const int* pi  = (const int*)d_in[10];
  const int* nu  = (const int*)d_in[11];
  const int* ni  = (const int*)d_in[12];
  const int* nbr = (const int*)d_in[13];

  float* wsf  = (float*)d_ws;
  int*   wsi  = (int*)d_ws;
  float* loss = wsf + OFF_LOSS;
  float* flag = wsf + OFF_FLAG;
  float* Wa   = wsf + OFF_WA;
  int*   cur  = wsi + OFF_CUR;
  int*   rtmp = wsi + OFF_RTMP;
  int*   bsum = wsi + OFF_BSUM;
  int*   boff = wsi + OFF_BOFF;
  int*   rowU = wsi + OFF_ROWU;
  int*   rowI = wsi + OFF_ROWI;
  int*   csrU = wsi + OFF_CSRU;
  int*   csrI = wsi + OFF_CSRI;
  float* u1   = wsf + OFF_U1;
  float* i1   = wsf + OFF_I1;
  float* hu   = wsf + OFF_HU;
  float* hi   = wsf + OFF_HI;
  float* anc  = wsf + OFF_ANC;

  constexpr int EB = (E_ + 255) / 256;  // 3907

  hipMemsetAsync(d_ws, 0, MEMSET_BYTES, stream);
  detect_kernel<<<1, 1, 0, stream>>>((const unsigned short*)ue, flag);
  wa_kernel<<<1, 64, 0, stream>>>(W, a, Wa, flag);

  // CSR build
  hist_kernel<<<EB, 256, 0, stream>>>(rs, rd, cur);
  scanA_kernel<<<NB_, 256, 0, stream>>>(cur, rtmp, bsum);
  scanB_kernel<<<1, 64, 0, stream>>>(bsum, boff);
  scanC_kernel<<<NB_, 256, 0, stream>>>(rtmp, boff, rowU, rowI, cur);
  fill_kernel<<<EB, 256, 0, stream>>>(rs, rd, cur, csrU, csrI);

  // layer-1 aggregation (gather)
  agg1_kernel<<<I_ / 4, 256, 0, stream>>>(ue, rowI, csrI, i1, flag);
  agg1_kernel<<<U_ / 4, 256, 0, stream>>>(ie, rowU, csrU, u1, flag);

  // layer-2 aggregation + fused layer attention
  agg2attn_kernel<<<I_ / 4, 256, 0, stream>>>(u1, ie, i1, rowI, csrI, Wa, hi, flag);
  agg2attn_kernel<<<U_ / 4, 256, 0, stream>>>(i1, ue, u1, rowU, csrU, Wa, hu, flag);

  // anchor path (independent of propagation)
  anchor_kernel<<<U_ / 4, 256, 0, stream>>>(ue, WU, aU, cw, nbr, anc, flag);

  // contrastive loss
  contrast_kernel<<<NCHUNK_, 256, 0, stream>>>(hu, anc, loss);

  // scores
  score_kernel<<<(2 * EP_ * 64) / 256, 256, 0, stream>>>(hu, hi, pu, pi, nu, ni, d_out, flag);
  finalize_kernel<<<1, 1, 0, stream>>>(loss, d_out, flag);
}